// Round 3
// baseline (213.715 us; speedup 1.0000x reference)
//
#include <hip/hip_runtime.h>
#include <hip/hip_bf16.h>
#include <stdint.h>

typedef __attribute__((ext_vector_type(4))) float  floatx4;
typedef __attribute__((ext_vector_type(8))) short  short8;
typedef __attribute__((ext_vector_type(8))) unsigned short ushortx8;
typedef __attribute__((ext_vector_type(4))) unsigned short ushortx4;

#define B_  2
#define T_  2048
#define E_  1024
#define H_  16
#define D_  64
#define C_  128
#define NC_ 16
#define M_  4096   /* B*T */
#define EPS_ 1e-5f

__device__ __forceinline__ unsigned short f2b(float f) {
    union { float f; unsigned int u; } v; v.f = f;
    unsigned int r = v.u + 0x7fffu + ((v.u >> 16) & 1u);
    return (unsigned short)(r >> 16);
}
__device__ __forceinline__ float b2f(unsigned short b) {
    union { unsigned int u; float f; } v; v.u = ((unsigned int)b) << 16;
    return v.f;
}

// ---------------- fp32 -> bf16 convert ----------------
__global__ __launch_bounds__(256) void convert_kernel(const float* __restrict__ src,
                                                      unsigned short* __restrict__ dst, int n) {
    int i = (blockIdx.x * 256 + threadIdx.x) * 4;
    if (i < n) {
        float4 f = *(const float4*)(src + i);
        ushortx4 o;
        o[0] = f2b(f.x); o[1] = f2b(f.y); o[2] = f2b(f.z); o[3] = f2b(f.w);
        *(ushortx4*)(dst + i) = o;
    }
}

// ---------------- QKV projection GEMM: C[4096,3072] = X @ W^T, phi on q,k ----------------
// LDS staged in MFMA-fragment order: tile t (16 rows x 32 k) occupies 1024B,
// slot i = (kseg q = i>>4, row m = i&15) -> fragment read = tile_base + lane*16B (linear,
// zero bank conflicts; round-2 row-major layout caused 4-way conflicts / 3.1M SQ_LDS_BANK_CONFLICT).
__global__ __launch_bounds__(256) void gemm_qkv(const unsigned short* __restrict__ A,
                                                const unsigned short* __restrict__ Bm,
                                                unsigned short* __restrict__ Cb) {
    const int N = 3 * E_, K = E_;
    __shared__ __align__(16) unsigned short at[8 * 512];
    __shared__ __align__(16) unsigned short bt[8 * 512];
    int tid = threadIdx.x;
    int wave = tid >> 6, lane = tid & 63;
    int wr = wave >> 1, wc = wave & 1;
    int m = lane & 15, q = lane >> 4;
    int row0 = blockIdx.y * 128, col0 = blockIdx.x * 128;
    floatx4 acc[4][4];
    for (int i = 0; i < 4; i++) for (int j = 0; j < 4; j++) acc[i][j] = floatx4{0.f, 0.f, 0.f, 0.f};

    for (int k0 = 0; k0 < K; k0 += 32) {
        __syncthreads();
        for (int p = 0; p < 2; p++) {
            int t = p * 4 + wave;
            const unsigned short* ga = A  + (size_t)(row0 + t * 16 + m) * K + k0 + q * 8;
            const unsigned short* gb = Bm + (size_t)(col0 + t * 16 + m) * K + k0 + q * 8;
            __builtin_amdgcn_global_load_lds((const __attribute__((address_space(1))) unsigned int*)ga,
                (__attribute__((address_space(3))) unsigned int*)(at + t * 512), 16, 0, 0);
            __builtin_amdgcn_global_load_lds((const __attribute__((address_space(1))) unsigned int*)gb,
                (__attribute__((address_space(3))) unsigned int*)(bt + t * 512), 16, 0, 0);
        }
        __syncthreads();
        short8 af[4], bfr[4];
        for (int mi = 0; mi < 4; mi++) af[mi]  = *(const short8*)(at + (wr * 4 + mi) * 512 + lane * 8);
        for (int ni = 0; ni < 4; ni++) bfr[ni] = *(const short8*)(bt + (wc * 4 + ni) * 512 + lane * 8);
        for (int mi = 0; mi < 4; mi++)
            for (int ni = 0; ni < 4; ni++)
                acc[mi][ni] = __builtin_amdgcn_mfma_f32_16x16x32_bf16(af[mi], bfr[ni], acc[mi][ni], 0, 0, 0);
    }
    int qrow = q * 4;
    for (int mi = 0; mi < 4; mi++) for (int ni = 0; ni < 4; ni++) {
        int col = col0 + wc * 64 + ni * 16 + m;
        bool isphi = (col < 2 * E_);
        for (int r2 = 0; r2 < 4; r2++) {
            int row = row0 + wr * 64 + mi * 16 + qrow + r2;
            float v = acc[mi][ni][r2];
            if (isphi) v = (v > 0.f) ? (v + 1.f) : __expf(v);
            Cb[(size_t)row * N + col] = f2b(v);
        }
    }
}

// ---------------- Output GEMM: out[4096,1024] = attn @ Wo^T + bo (fp32 out) ----------------
// 64x128 block tile (512 blocks = 2/CU; 128x128 gave only 1/CU -> no latency hiding).
// Wave w computes all 64 rows x cols [w*32, w*32+32). Fragment-order LDS as in gemm_qkv.
__global__ __launch_bounds__(256) void gemm_out(const unsigned short* __restrict__ A,
                                                const unsigned short* __restrict__ Bm,
                                                const float* __restrict__ bias,
                                                float* __restrict__ Cf) {
    const int N = E_, K = E_;
    __shared__ __align__(16) unsigned short at[4 * 512];
    __shared__ __align__(16) unsigned short bt[8 * 512];
    int tid = threadIdx.x;
    int wave = tid >> 6, lane = tid & 63;
    int m = lane & 15, q = lane >> 4;
    int row0 = blockIdx.y * 64, col0 = blockIdx.x * 128;
    floatx4 acc[4][2];
    for (int i = 0; i < 4; i++) for (int j = 0; j < 2; j++) acc[i][j] = floatx4{0.f, 0.f, 0.f, 0.f};

    for (int k0 = 0; k0 < K; k0 += 32) {
        __syncthreads();
        {
            const unsigned short* ga  = A  + (size_t)(row0 + wave * 16 + m) * K + k0 + q * 8;
            __builtin_amdgcn_global_load_lds((const __attribute__((address_space(1))) unsigned int*)ga,
                (__attribute__((address_space(3))) unsigned int*)(at + wave * 512), 16, 0, 0);
            for (int p = 0; p < 2; p++) {
                int t = wave * 2 + p;
                const unsigned short* gb = Bm + (size_t)(col0 + t * 16 + m) * K + k0 + q * 8;
                __builtin_amdgcn_global_load_lds((const __attribute__((address_space(1))) unsigned int*)gb,
                    (__attribute__((address_space(3))) unsigned int*)(bt + t * 512), 16, 0, 0);
            }
        }
        __syncthreads();
        short8 af[4], bfr[2];
        for (int mi = 0; mi < 4; mi++) af[mi]  = *(const short8*)(at + mi * 512 + lane * 8);
        for (int ci = 0; ci < 2; ci++) bfr[ci] = *(const short8*)(bt + (wave * 2 + ci) * 512 + lane * 8);
        for (int mi = 0; mi < 4; mi++)
            for (int ci = 0; ci < 2; ci++)
                acc[mi][ci] = __builtin_amdgcn_mfma_f32_16x16x32_bf16(af[mi], bfr[ci], acc[mi][ci], 0, 0, 0);
    }
    int qrow = q * 4;
    for (int ci = 0; ci < 2; ci++) {
        int col = col0 + wave * 32 + ci * 16 + m;
        float bv = bias[col];
        for (int mi = 0; mi < 4; mi++)
            for (int r2 = 0; r2 < 4; r2++) {
                int row = row0 + mi * 16 + qrow + r2;
                Cf[(size_t)row * N + col] = acc[mi][ci][r2] + bv;
            }
    }
}

// ---------------- per-chunk S_c = k_c^T v_c (64x64) and z_c (MFMA) ----------------
// A = K^T (m=d, k=t), B = V (k=t, n=e); extra n-col 64 = ones -> z_c.
__global__ __launch_bounds__(256) void chunk_sums(const unsigned short* __restrict__ qkv,
                                                  float* __restrict__ Sc, float* __restrict__ zc) {
    int c = blockIdx.x, h = blockIdx.y, bb = blockIdx.z;
    __shared__ __align__(16) unsigned short Kt[64 * 132];   // K^T: [d][t], stride 132 (conflict-free)
    __shared__ __align__(16) unsigned short Vt[80 * 132];   // V^T rows 0..63; row 64 = ones
    int tid = threadIdx.x;
    int lane = tid & 63, w = tid >> 6;
    size_t rowb = (size_t)bb * T_ + (size_t)c * C_;
    int kcol = E_ + h * D_, vcol = 2 * E_ + h * D_;

    for (int s = 0; s < 4; s++) {
        int off = s * 256 + tid;
        int r = off >> 3, seg = (off & 7) * 8;
        size_t g = (rowb + r) * 3072;
        ushortx8 k8 = *(const ushortx8*)(qkv + g + kcol + seg);
        ushortx8 v8 = *(const ushortx8*)(qkv + g + vcol + seg);
        for (int e = 0; e < 8; e++) {
            Kt[(seg + e) * 132 + r] = k8[e];
            Vt[(seg + e) * 132 + r] = v8[e];
        }
    }
    if (tid < 128) Vt[64 * 132 + tid] = 0x3f80;  // ones row (bf16 1.0)
    __syncthreads();

    floatx4 acc[5];
    for (int ni = 0; ni < 5; ni++) acc[ni] = floatx4{0.f, 0.f, 0.f, 0.f};
    int lm = lane & 15, lk = (lane >> 4) * 8;
    for (int k0 = 0; k0 < 128; k0 += 32) {
        short8 af = *(const short8*)(Kt + (w * 16 + lm) * 132 + k0 + lk);
        for (int ni = 0; ni < 5; ni++) {
            short8 bf = *(const short8*)(Vt + (ni * 16 + lm) * 132 + k0 + lk);
            acc[ni] = __builtin_amdgcn_mfma_f32_16x16x32_bf16(af, bf, acc[ni], 0, 0, 0);
        }
    }
    size_t base = ((size_t)(bb * H_ + h) * NC_ + c) * (size_t)(D_ * D_);
    int r0 = w * 16 + (lane >> 4) * 4;
    for (int ni = 0; ni < 4; ni++)
        for (int reg = 0; reg < 4; reg++)
            Sc[base + (size_t)(r0 + reg) * D_ + ni * 16 + lm] = acc[ni][reg];
    if (lm == 0) {
        size_t zb = ((size_t)(bb * H_ + h) * NC_ + c) * D_;
        for (int reg = 0; reg < 4; reg++) zc[zb + r0 + reg] = acc[4][reg];
    }
}

// ---------------- per-chunk attention (MFMA) ----------------
__global__ __launch_bounds__(256) void attn_kernel(const unsigned short* __restrict__ qkv,
                                                   const float* __restrict__ Sc,
                                                   const float* __restrict__ zc,
                                                   unsigned short* __restrict__ attn) {
    int c = blockIdx.x, h = blockIdx.y, bb = blockIdx.z;
    __shared__ __align__(16) unsigned short qs[128 * 68];   // Q row-major, stride 68 (shift 2 dw/row)
    __shared__ __align__(16) unsigned short ks[128 * 68];   // K row-major
    __shared__ __align__(16) unsigned short vt[64 * 132];   // V^T
    __shared__ __align__(16) unsigned short ovl[128 * 36];  // phase A: S_prev^T (stride 68); j-loop: P panel (stride 36)
    __shared__ float zsh[64];
    int tid = threadIdx.x;
    int lane = tid & 63, w = tid >> 6;
    int lm = lane & 15, lq = lane >> 4;
    size_t rowb = (size_t)bb * T_ + (size_t)c * C_;
    int qcol = h * D_, kcol = E_ + h * D_, vcol = 2 * E_ + h * D_;

    // ---- stage q, k (row-major) and v (transposed) ----
    for (int s = 0; s < 4; s++) {
        int off = s * 256 + tid;
        int r = off >> 3, seg = (off & 7) * 8;
        size_t g = (rowb + r) * 3072;
        ushortx8 q8 = *(const ushortx8*)(qkv + g + qcol + seg);
        ushortx8 k8 = *(const ushortx8*)(qkv + g + kcol + seg);
        ushortx8 v8 = *(const ushortx8*)(qkv + g + vcol + seg);
        *(ushortx8*)(qs + r * 68 + seg) = q8;
        *(ushortx8*)(ks + r * 68 + seg) = k8;
        for (int e = 0; e < 8; e++) vt[(seg + e) * 132 + r] = v8[e];
    }
    // ---- S_prev = sum_{j<c} Sc[j]  (store transposed bf16 into ovl, stride 68) ----
    {
        size_t scb = ((size_t)(bb * H_ + h) * NC_) * (size_t)(D_ * D_);
        int p = tid * 16;
        float a[16];
        for (int i = 0; i < 16; i++) a[i] = 0.f;
        for (int j = 0; j < c; j++) {
            const float* Sj = Sc + scb + (size_t)j * (D_ * D_) + p;
            for (int q = 0; q < 16; q += 4) {
                float4 f = *(const float4*)(Sj + q);
                a[q] += f.x; a[q + 1] += f.y; a[q + 2] += f.z; a[q + 3] += f.w;
            }
        }
        for (int i = 0; i < 16; i++) {
            int d = (p + i) >> 6, e = (p + i) & 63;
            ovl[e * 68 + d] = f2b(a[i]);
        }
    }
    // ---- z_prev (fp32) ----
    if (tid < 64) {
        size_t zb = ((size_t)(bb * H_ + h) * NC_) * D_;
        float zr = 0.f;
        for (int j = 0; j < c; j++) zr += zc[zb + (size_t)j * D_ + tid];
        zsh[tid] = zr;
    }
    __syncthreads();

    // ---- phase A: acc = Q @ S_prev  (wave w -> rows [w*32, w*32+32)) ----
    floatx4 acc[2][4];
    for (int mi = 0; mi < 2; mi++) for (int ni = 0; ni < 4; ni++) acc[mi][ni] = floatx4{0.f, 0.f, 0.f, 0.f};
    for (int k0 = 0; k0 < 64; k0 += 32) {
        short8 aq[2];
        for (int mi = 0; mi < 2; mi++)
            aq[mi] = *(const short8*)(qs + (w * 32 + mi * 16 + lm) * 68 + k0 + lq * 8);
        for (int ni = 0; ni < 4; ni++) {
            short8 bs = *(const short8*)(ovl + (ni * 16 + lm) * 68 + k0 + lq * 8);
            for (int mi = 0; mi < 2; mi++)
                acc[mi][ni] = __builtin_amdgcn_mfma_f32_16x16x32_bf16(aq[mi], bs, acc[mi][ni], 0, 0, 0);
        }
    }
    // ---- dsum init: q . z_prev per output row (C-layout rows), fp32 ----
    float dsum[2][4];
    {
        int d0 = lm * 4;
        float4 z4 = *(const float4*)(zsh + d0);
        for (int mi = 0; mi < 2; mi++)
            for (int reg = 0; reg < 4; reg++) {
                int row = w * 32 + mi * 16 + lq * 4 + reg;
                ushortx4 q4 = *(const ushortx4*)(qs + row * 68 + d0);
                dsum[mi][reg] = b2f(q4[0]) * z4.x + b2f(q4[1]) * z4.y + b2f(q4[2]) * z4.z + b2f(q4[3]) * z4.w;
            }
    }
    __syncthreads();  // all waves done reading S_prev^T from ovl before P writes

    // ---- intra-chunk j-loop: wave w only needs j-tiles jt <= w (causality) ----
    for (int jt = 0; jt <= w; jt++) {
        floatx4 pa[2][2];
        for (int mi = 0; mi < 2; mi++) for (int ct = 0; ct < 2; ct++) pa[mi][ct] = floatx4{0.f, 0.f, 0.f, 0.f};
        for (int k0 = 0; k0 < 64; k0 += 32) {
            short8 aq[2];
            for (int mi = 0; mi < 2; mi++)
                aq[mi] = *(const short8*)(qs + (w * 32 + mi * 16 + lm) * 68 + k0 + lq * 8);
            for (int ct = 0; ct < 2; ct++) {
                short8 bk = *(const short8*)(ks + (jt * 32 + ct * 16 + lm) * 68 + k0 + lq * 8);
                for (int mi = 0; mi < 2; mi++)
                    pa[mi][ct] = __builtin_amdgcn_mfma_f32_16x16x32_bf16(aq[mi], bk, pa[mi][ct], 0, 0, 0);
            }
        }
        bool diag = (jt == w);
        for (int mi = 0; mi < 2; mi++)
            for (int ct = 0; ct < 2; ct++)
                for (int reg = 0; reg < 4; reg++) {
                    int il = mi * 16 + lq * 4 + reg;   // row within wave's 32
                    int jl = ct * 16 + lm;             // col within j-tile's 32
                    float v = pa[mi][ct][reg];
                    if (diag && jl > il) v = 0.f;
                    dsum[mi][reg] += v;
                    ovl[(w * 32 + il) * 36 + jl] = f2b(v);
                }
        // PV: P (A-layout from own rows of ovl) x V^T slice, K=32
        short8 ap[2];
        for (int mi = 0; mi < 2; mi++)
            ap[mi] = *(const short8*)(ovl + (w * 32 + mi * 16 + lm) * 36 + lq * 8);
        for (int ni = 0; ni < 4; ni++) {
            short8 bv = *(const short8*)(vt + (ni * 16 + lm) * 132 + jt * 32 + lq * 8);
            for (int mi = 0; mi < 2; mi++)
                acc[mi][ni] = __builtin_amdgcn_mfma_f32_16x16x32_bf16(ap[mi], bv, acc[mi][ni], 0, 0, 0);
        }
    }

    // ---- reduce dsum across the 16-lane col group ----
    for (int off = 1; off < 16; off <<= 1)
        for (int mi = 0; mi < 2; mi++)
            for (int reg = 0; reg < 4; reg++)
                dsum[mi][reg] += __shfl_xor(dsum[mi][reg], off);

    // ---- epilogue: out = num / den ----
    for (int mi = 0; mi < 2; mi++)
        for (int reg = 0; reg < 4; reg++) {
            float inv = 1.f / (dsum[mi][reg] + EPS_);
            int row = w * 32 + mi * 16 + lq * 4 + reg;
            for (int ni = 0; ni < 4; ni++)
                attn[(rowb + row) * E_ + h * D_ + ni * 16 + lm] = f2b(acc[mi][ni][reg] * inv);
        }
}

extern "C" void kernel_launch(void* const* d_in, const int* in_sizes, int n_in,
                              void* d_out, int out_size, void* d_ws, size_t ws_size,
                              hipStream_t stream) {
    const float* x  = (const float*)d_in[0];
    const float* Wq = (const float*)d_in[1];
    const float* Wk = (const float*)d_in[2];
    const float* Wv = (const float*)d_in[3];
    const float* Wo = (const float*)d_in[4];
    const float* bo = (const float*)d_in[5];
    float* out = (float*)d_out;

    const size_t MB = 1024 * 1024;
    uint8_t* ws = (uint8_t*)d_ws;
    unsigned short* xb    = (unsigned short*)(ws + 0);        // 8 MB, reused as attn buffer
    unsigned short* wb    = (unsigned short*)(ws + 8 * MB);   // 6 MB (Wq|Wk|Wv bf16)
    unsigned short* wob   = (unsigned short*)(ws + 14 * MB);  // 2 MB
    unsigned short* qkvb  = (unsigned short*)(ws + 16 * MB);  // 24 MB
    float* Sc = (float*)(ws + 40 * MB);                       // 8 MB
    float* zc = (float*)(ws + 48 * MB);                       // 128 KB
    unsigned short* attnb = xb;

    convert_kernel<<<(M_ * E_) / 1024, 256, 0, stream>>>(x, xb, M_ * E_);
    convert_kernel<<<(E_ * E_) / 1024, 256, 0, stream>>>(Wq, wb,              E_ * E_);
    convert_kernel<<<(E_ * E_) / 1024, 256, 0, stream>>>(Wk, wb + E_ * E_,    E_ * E_);
    convert_kernel<<<(E_ * E_) / 1024, 256, 0, stream>>>(Wv, wb + 2 * E_ * E_, E_ * E_);
    convert_kernel<<<(E_ * E_) / 1024, 256, 0, stream>>>(Wo, wob, E_ * E_);

    gemm_qkv<<<dim3(24, 32), 256, 0, stream>>>(xb, wb, qkvb);
    chunk_sums<<<dim3(NC_, H_, B_), 256, 0, stream>>>(qkvb, Sc, zc);
    attn_kernel<<<dim3(NC_, H_, B_), 256, 0, stream>>>(qkvb, Sc, zc, attnb);
    gemm_out<<<dim3(8, 64), 256, 0, stream>>>(attnb, wob, bo, out);
}

// Round 4
// 188.012 us; speedup vs baseline: 1.1367x; 1.1367x over previous
//
#include <hip/hip_runtime.h>
#include <hip/hip_bf16.h>
#include <stdint.h>

typedef __attribute__((ext_vector_type(4))) float  floatx4;
typedef __attribute__((ext_vector_type(8))) short  short8;
typedef __attribute__((ext_vector_type(8))) unsigned short ushortx8;
typedef __attribute__((ext_vector_type(4))) unsigned short ushortx4;

#define B_  2
#define T_  2048
#define E_  1024
#define H_  16
#define D_  64
#define C_  128
#define NC_ 16
#define M_  4096   /* B*T */
#define EPS_ 1e-5f

__device__ __forceinline__ unsigned short f2b(float f) {
    union { float f; unsigned int u; } v; v.f = f;
    unsigned int r = v.u + 0x7fffu + ((v.u >> 16) & 1u);
    return (unsigned short)(r >> 16);
}
__device__ __forceinline__ float b2f(unsigned short b) {
    union { unsigned int u; float f; } v; v.u = ((unsigned int)b) << 16;
    return v.f;
}

// Swizzled fragment staging (see R3 post-mortem):
//   staging lane i fetches global (row = i>>2, kseg = (i&3) ^ ((i>>3)&3)) -> LDS slot i (16B).
//   4-lane clusters cover one contiguous 64B line (global coalescing = R2 layout),
//   fragment read slot sigma(l) = m*4 + (q ^ ((m>>1)&3)) covers all 8 bank-quads per
//   8 lanes (zero LDS conflicts = R3 layout). sigma holds (row m, seg q) exactly.
__device__ __forceinline__ int stage_seg(int i) { return (i & 3) ^ ((i >> 3) & 3); }
__device__ __forceinline__ int frag_slot(int lane) {
    int m = lane & 15, q = lane >> 4;
    return m * 4 + (q ^ ((m >> 1) & 3));
}

// ---------------- fp32 -> bf16 convert ----------------
__global__ __launch_bounds__(256) void convert_kernel(const float* __restrict__ src,
                                                      unsigned short* __restrict__ dst, int n) {
    int i = (blockIdx.x * 256 + threadIdx.x) * 4;
    if (i < n) {
        float4 f = *(const float4*)(src + i);
        ushortx4 o;
        o[0] = f2b(f.x); o[1] = f2b(f.y); o[2] = f2b(f.z); o[3] = f2b(f.w);
        *(ushortx4*)(dst + i) = o;
    }
}

// ---------------- QKV projection GEMM: C[4096,3072] = X @ W^T, phi on q,k ----------------
__global__ __launch_bounds__(256) void gemm_qkv(const unsigned short* __restrict__ A,
                                                const unsigned short* __restrict__ Bm,
                                                unsigned short* __restrict__ Cb) {
    const int N = 3 * E_, K = E_;
    __shared__ __align__(16) unsigned short at[8 * 512];
    __shared__ __align__(16) unsigned short bt[8 * 512];
    int tid = threadIdx.x;
    int wave = tid >> 6, lane = tid & 63;
    int wr = wave >> 1, wc = wave & 1;
    int m = lane & 15, q = lane >> 4;
    int srow = lane >> 2, sseg = stage_seg(lane);
    int fs = frag_slot(lane);
    int row0 = blockIdx.y * 128, col0 = blockIdx.x * 128;
    floatx4 acc[4][4];
    for (int i = 0; i < 4; i++) for (int j = 0; j < 4; j++) acc[i][j] = floatx4{0.f, 0.f, 0.f, 0.f};

    for (int k0 = 0; k0 < K; k0 += 32) {
        __syncthreads();
        for (int p = 0; p < 2; p++) {
            int t = p * 4 + wave;
            const unsigned short* ga = A  + (size_t)(row0 + t * 16 + srow) * K + k0 + sseg * 8;
            const unsigned short* gb = Bm + (size_t)(col0 + t * 16 + srow) * K + k0 + sseg * 8;
            __builtin_amdgcn_global_load_lds((const __attribute__((address_space(1))) unsigned int*)ga,
                (__attribute__((address_space(3))) unsigned int*)(at + t * 512), 16, 0, 0);
            __builtin_amdgcn_global_load_lds((const __attribute__((address_space(1))) unsigned int*)gb,
                (__attribute__((address_space(3))) unsigned int*)(bt + t * 512), 16, 0, 0);
        }
        __syncthreads();
        short8 af[4], bfr[4];
        for (int mi = 0; mi < 4; mi++) af[mi]  = *(const short8*)(at + (wr * 4 + mi) * 512 + fs * 8);
        for (int ni = 0; ni < 4; ni++) bfr[ni] = *(const short8*)(bt + (wc * 4 + ni) * 512 + fs * 8);
        for (int mi = 0; mi < 4; mi++)
            for (int ni = 0; ni < 4; ni++)
                acc[mi][ni] = __builtin_amdgcn_mfma_f32_16x16x32_bf16(af[mi], bfr[ni], acc[mi][ni], 0, 0, 0);
    }
    int qrow = q * 4;
    for (int mi = 0; mi < 4; mi++) for (int ni = 0; ni < 4; ni++) {
        int col = col0 + wc * 64 + ni * 16 + m;
        bool isphi = (col < 2 * E_);
        for (int r2 = 0; r2 < 4; r2++) {
            int row = row0 + wr * 64 + mi * 16 + qrow + r2;
            float v = acc[mi][ni][r2];
            if (isphi) v = (v > 0.f) ? (v + 1.f) : __expf(v);
            Cb[(size_t)row * N + col] = f2b(v);
        }
    }
}

// ---------------- Output GEMM: out[4096,1024] = attn @ Wo^T + bo (fp32 out) ----------------
// 64x128 block tile (512 blocks = 2/CU). Swizzled fragment staging as in gemm_qkv.
__global__ __launch_bounds__(256) void gemm_out(const unsigned short* __restrict__ A,
                                                const unsigned short* __restrict__ Bm,
                                                const float* __restrict__ bias,
                                                float* __restrict__ Cf) {
    const int N = E_, K = E_;
    __shared__ __align__(16) unsigned short at[4 * 512];
    __shared__ __align__(16) unsigned short bt[8 * 512];
    int tid = threadIdx.x;
    int wave = tid >> 6, lane = tid & 63;
    int m = lane & 15, q = lane >> 4;
    int srow = lane >> 2, sseg = stage_seg(lane);
    int fs = frag_slot(lane);
    int row0 = blockIdx.y * 64, col0 = blockIdx.x * 128;
    floatx4 acc[4][2];
    for (int i = 0; i < 4; i++) for (int j = 0; j < 2; j++) acc[i][j] = floatx4{0.f, 0.f, 0.f, 0.f};

    for (int k0 = 0; k0 < K; k0 += 32) {
        __syncthreads();
        {
            const unsigned short* ga  = A  + (size_t)(row0 + wave * 16 + srow) * K + k0 + sseg * 8;
            __builtin_amdgcn_global_load_lds((const __attribute__((address_space(1))) unsigned int*)ga,
                (__attribute__((address_space(3))) unsigned int*)(at + wave * 512), 16, 0, 0);
            for (int p = 0; p < 2; p++) {
                int t = wave * 2 + p;
                const unsigned short* gb = Bm + (size_t)(col0 + t * 16 + srow) * K + k0 + sseg * 8;
                __builtin_amdgcn_global_load_lds((const __attribute__((address_space(1))) unsigned int*)gb,
                    (__attribute__((address_space(3))) unsigned int*)(bt + t * 512), 16, 0, 0);
            }
        }
        __syncthreads();
        short8 af[4], bfr[2];
        for (int mi = 0; mi < 4; mi++) af[mi]  = *(const short8*)(at + mi * 512 + fs * 8);
        for (int ci = 0; ci < 2; ci++) bfr[ci] = *(const short8*)(bt + (wave * 2 + ci) * 512 + fs * 8);
        for (int mi = 0; mi < 4; mi++)
            for (int ci = 0; ci < 2; ci++)
                acc[mi][ci] = __builtin_amdgcn_mfma_f32_16x16x32_bf16(af[mi], bfr[ci], acc[mi][ci], 0, 0, 0);
    }
    int qrow = q * 4;
    for (int ci = 0; ci < 2; ci++) {
        int col = col0 + wave * 32 + ci * 16 + m;
        float bv = bias[col];
        for (int mi = 0; mi < 4; mi++)
            for (int r2 = 0; r2 < 4; r2++) {
                int row = row0 + mi * 16 + qrow + r2;
                Cf[(size_t)row * N + col] = acc[mi][ci][r2] + bv;
            }
    }
}

// ---------------- per-chunk S_c = k_c^T v_c (64x64) and z_c (MFMA) ----------------
// A = K^T (m=d, k=t), B = V (k=t, n=e); extra n-col 64 = ones -> z_c.
__global__ __launch_bounds__(256) void chunk_sums(const unsigned short* __restrict__ qkv,
                                                  float* __restrict__ Sc, float* __restrict__ zc) {
    int c = blockIdx.x, h = blockIdx.y, bb = blockIdx.z;
    __shared__ __align__(16) unsigned short Kt[64 * 132];   // K^T: [d][t], stride 132 (conflict-free)
    __shared__ __align__(16) unsigned short Vt[80 * 132];   // V^T rows 0..63; row 64 = ones
    int tid = threadIdx.x;
    int lane = tid & 63, w = tid >> 6;
    size_t rowb = (size_t)bb * T_ + (size_t)c * C_;
    int kcol = E_ + h * D_, vcol = 2 * E_ + h * D_;

    for (int s = 0; s < 4; s++) {
        int off = s * 256 + tid;
        int r = off >> 3, seg = (off & 7) * 8;
        size_t g = (rowb + r) * 3072;
        ushortx8 k8 = *(const ushortx8*)(qkv + g + kcol + seg);
        ushortx8 v8 = *(const ushortx8*)(qkv + g + vcol + seg);
        for (int e = 0; e < 8; e++) {
            Kt[(seg + e) * 132 + r] = k8[e];
            Vt[(seg + e) * 132 + r] = v8[e];
        }
    }
    if (tid < 128) Vt[64 * 132 + tid] = 0x3f80;  // ones row (bf16 1.0)
    __syncthreads();

    floatx4 acc[5];
    for (int ni = 0; ni < 5; ni++) acc[ni] = floatx4{0.f, 0.f, 0.f, 0.f};
    int lm = lane & 15, lk = (lane >> 4) * 8;
    for (int k0 = 0; k0 < 128; k0 += 32) {
        short8 af = *(const short8*)(Kt + (w * 16 + lm) * 132 + k0 + lk);
        for (int ni = 0; ni < 5; ni++) {
            short8 bf = *(const short8*)(Vt + (ni * 16 + lm) * 132 + k0 + lk);
            acc[ni] = __builtin_amdgcn_mfma_f32_16x16x32_bf16(af, bf, acc[ni], 0, 0, 0);
        }
    }
    size_t base = ((size_t)(bb * H_ + h) * NC_ + c) * (size_t)(D_ * D_);
    int r0 = w * 16 + (lane >> 4) * 4;
    for (int ni = 0; ni < 4; ni++)
        for (int reg = 0; reg < 4; reg++)
            Sc[base + (size_t)(r0 + reg) * D_ + ni * 16 + lm] = acc[ni][reg];
    if (lm == 0) {
        size_t zb = ((size_t)(bb * H_ + h) * NC_ + c) * D_;
        for (int reg = 0; reg < 4; reg++) zc[zb + r0 + reg] = acc[4][reg];
    }
}

// ---------------- per-chunk attention (MFMA) ----------------
__global__ __launch_bounds__(256) void attn_kernel(const unsigned short* __restrict__ qkv,
                                                   const float* __restrict__ Sc,
                                                   const float* __restrict__ zc,
                                                   unsigned short* __restrict__ attn) {
    int c = blockIdx.x, h = blockIdx.y, bb = blockIdx.z;
    __shared__ __align__(16) unsigned short qs[128 * 68];   // Q row-major, stride 68 (shift 2 dw/row)
    __shared__ __align__(16) unsigned short ks[128 * 68];   // K row-major
    __shared__ __align__(16) unsigned short vt[64 * 132];   // V^T
    __shared__ __align__(16) unsigned short ovl[128 * 36];  // phase A: S_prev^T (stride 68); j-loop: P panel (stride 36)
    __shared__ float zsh[64];
    int tid = threadIdx.x;
    int lane = tid & 63, w = tid >> 6;
    int lm = lane & 15, lq = lane >> 4;
    size_t rowb = (size_t)bb * T_ + (size_t)c * C_;
    int qcol = h * D_, kcol = E_ + h * D_, vcol = 2 * E_ + h * D_;

    // ---- stage q, k (row-major) and v (transposed) ----
    for (int s = 0; s < 4; s++) {
        int off = s * 256 + tid;
        int r = off >> 3, seg = (off & 7) * 8;
        size_t g = (rowb + r) * 3072;
        ushortx8 q8 = *(const ushortx8*)(qkv + g + qcol + seg);
        ushortx8 k8 = *(const ushortx8*)(qkv + g + kcol + seg);
        ushortx8 v8 = *(const ushortx8*)(qkv + g + vcol + seg);
        *(ushortx8*)(qs + r * 68 + seg) = q8;
        *(ushortx8*)(ks + r * 68 + seg) = k8;
        for (int e = 0; e < 8; e++) vt[(seg + e) * 132 + r] = v8[e];
    }
    // ---- S_prev = sum_{j<c} Sc[j]  (store transposed bf16 into ovl, stride 68) ----
    {
        size_t scb = ((size_t)(bb * H_ + h) * NC_) * (size_t)(D_ * D_);
        int p = tid * 16;
        float a[16];
        for (int i = 0; i < 16; i++) a[i] = 0.f;
        for (int j = 0; j < c; j++) {
            const float* Sj = Sc + scb + (size_t)j * (D_ * D_) + p;
            for (int q = 0; q < 16; q += 4) {
                float4 f = *(const float4*)(Sj + q);
                a[q] += f.x; a[q + 1] += f.y; a[q + 2] += f.z; a[q + 3] += f.w;
            }
        }
        for (int i = 0; i < 16; i++) {
            int d = (p + i) >> 6, e = (p + i) & 63;
            ovl[e * 68 + d] = f2b(a[i]);
        }
    }
    // ---- z_prev (fp32) ----
    if (tid < 64) {
        size_t zb = ((size_t)(bb * H_ + h) * NC_) * D_;
        float zr = 0.f;
        for (int j = 0; j < c; j++) zr += zc[zb + (size_t)j * D_ + tid];
        zsh[tid] = zr;
    }
    __syncthreads();

    // ---- phase A: acc = Q @ S_prev  (wave w -> rows [w*32, w*32+32)) ----
    floatx4 acc[2][4];
    for (int mi = 0; mi < 2; mi++) for (int ni = 0; ni < 4; ni++) acc[mi][ni] = floatx4{0.f, 0.f, 0.f, 0.f};
    for (int k0 = 0; k0 < 64; k0 += 32) {
        short8 aq[2];
        for (int mi = 0; mi < 2; mi++)
            aq[mi] = *(const short8*)(qs + (w * 32 + mi * 16 + lm) * 68 + k0 + lq * 8);
        for (int ni = 0; ni < 4; ni++) {
            short8 bs = *(const short8*)(ovl + (ni * 16 + lm) * 68 + k0 + lq * 8);
            for (int mi = 0; mi < 2; mi++)
                acc[mi][ni] = __builtin_amdgcn_mfma_f32_16x16x32_bf16(aq[mi], bs, acc[mi][ni], 0, 0, 0);
        }
    }
    // ---- dsum init: q . z_prev per output row (C-layout rows), fp32 ----
    float dsum[2][4];
    {
        int d0 = lm * 4;
        float4 z4 = *(const float4*)(zsh + d0);
        for (int mi = 0; mi < 2; mi++)
            for (int reg = 0; reg < 4; reg++) {
                int row = w * 32 + mi * 16 + lq * 4 + reg;
                ushortx4 q4 = *(const ushortx4*)(qs + row * 68 + d0);
                dsum[mi][reg] = b2f(q4[0]) * z4.x + b2f(q4[1]) * z4.y + b2f(q4[2]) * z4.z + b2f(q4[3]) * z4.w;
            }
    }
    __syncthreads();  // all waves done reading S_prev^T from ovl before P writes

    // ---- intra-chunk j-loop: wave w only needs j-tiles jt <= w (causality) ----
    for (int jt = 0; jt <= w; jt++) {
        floatx4 pa[2][2];
        for (int mi = 0; mi < 2; mi++) for (int ct = 0; ct < 2; ct++) pa[mi][ct] = floatx4{0.f, 0.f, 0.f, 0.f};
        for (int k0 = 0; k0 < 64; k0 += 32) {
            short8 aq[2];
            for (int mi = 0; mi < 2; mi++)
                aq[mi] = *(const short8*)(qs + (w * 32 + mi * 16 + lm) * 68 + k0 + lq * 8);
            for (int ct = 0; ct < 2; ct++) {
                short8 bk = *(const short8*)(ks + (jt * 32 + ct * 16 + lm) * 68 + k0 + lq * 8);
                for (int mi = 0; mi < 2; mi++)
                    pa[mi][ct] = __builtin_amdgcn_mfma_f32_16x16x32_bf16(aq[mi], bk, pa[mi][ct], 0, 0, 0);
            }
        }
        bool diag = (jt == w);
        for (int mi = 0; mi < 2; mi++)
            for (int ct = 0; ct < 2; ct++)
                for (int reg = 0; reg < 4; reg++) {
                    int il = mi * 16 + lq * 4 + reg;   // row within wave's 32
                    int jl = ct * 16 + lm;             // col within j-tile's 32
                    float v = pa[mi][ct][reg];
                    if (diag && jl > il) v = 0.f;
                    dsum[mi][reg] += v;
                    ovl[(w * 32 + il) * 36 + jl] = f2b(v);
                }
        // PV: P (A-layout from own rows of ovl) x V^T slice, K=32
        short8 ap[2];
        for (int mi = 0; mi < 2; mi++)
            ap[mi] = *(const short8*)(ovl + (w * 32 + mi * 16 + lm) * 36 + lq * 8);
        for (int ni = 0; ni < 4; ni++) {
            short8 bv = *(const short8*)(vt + (ni * 16 + lm) * 132 + jt * 32 + lq * 8);
            for (int mi = 0; mi < 2; mi++)
                acc[mi][ni] = __builtin_amdgcn_mfma_f32_16x16x32_bf16(ap[mi], bv, acc[mi][ni], 0, 0, 0);
        }
    }

    // ---- reduce dsum across the 16-lane col group ----
    for (int off = 1; off < 16; off <<= 1)
        for (int mi = 0; mi < 2; mi++)
            for (int reg = 0; reg < 4; reg++)
                dsum[mi][reg] += __shfl_xor(dsum[mi][reg], off);

    // ---- epilogue: out = num / den ----
    for (int mi = 0; mi < 2; mi++)
        for (int reg = 0; reg < 4; reg++) {
            float inv = 1.f / (dsum[mi][reg] + EPS_);
            int row = w * 32 + mi * 16 + lq * 4 + reg;
            for (int ni = 0; ni < 4; ni++)
                attn[(rowb + row) * E_ + h * D_ + ni * 16 + lm] = f2b(acc[mi][ni][reg] * inv);
        }
}

extern "C" void kernel_launch(void* const* d_in, const int* in_sizes, int n_in,
                              void* d_out, int out_size, void* d_ws, size_t ws_size,
                              hipStream_t stream) {
    const float* x  = (const float*)d_in[0];
    const float* Wq = (const float*)d_in[1];
    const float* Wk = (const float*)d_in[2];
    const float* Wv = (const float*)d_in[3];
    const float* Wo = (const float*)d_in[4];
    const float* bo = (const float*)d_in[5];
    float* out = (float*)d_out;

    const size_t MB = 1024 * 1024;
    uint8_t* ws = (uint8_t*)d_ws;
    unsigned short* xb    = (unsigned short*)(ws + 0);        // 8 MB, reused as attn buffer
    unsigned short* wb    = (unsigned short*)(ws + 8 * MB);   // 6 MB (Wq|Wk|Wv bf16)
    unsigned short* wob   = (unsigned short*)(ws + 14 * MB);  // 2 MB
    unsigned short* qkvb  = (unsigned short*)(ws + 16 * MB);  // 24 MB
    float* Sc = (float*)(ws + 40 * MB);                       // 8 MB
    float* zc = (float*)(ws + 48 * MB);                       // 128 KB
    unsigned short* attnb = xb;

    convert_kernel<<<(M_ * E_) / 1024, 256, 0, stream>>>(x, xb, M_ * E_);
    convert_kernel<<<(E_ * E_) / 1024, 256, 0, stream>>>(Wq, wb,              E_ * E_);
    convert_kernel<<<(E_ * E_) / 1024, 256, 0, stream>>>(Wk, wb + E_ * E_,    E_ * E_);
    convert_kernel<<<(E_ * E_) / 1024, 256, 0, stream>>>(Wv, wb + 2 * E_ * E_, E_ * E_);
    convert_kernel<<<(E_ * E_) / 1024, 256, 0, stream>>>(Wo, wob, E_ * E_);

    gemm_qkv<<<dim3(24, 32), 256, 0, stream>>>(xb, wb, qkvb);
    chunk_sums<<<dim3(NC_, H_, B_), 256, 0, stream>>>(qkvb, Sc, zc);
    attn_kernel<<<dim3(NC_, H_, B_), 256, 0, stream>>>(qkvb, Sc, zc, attnb);
    gemm_out<<<dim3(8, 64), 256, 0, stream>>>(attnb, wob, bo, out);
}

// Round 5
// 174.945 us; speedup vs baseline: 1.2216x; 1.0747x over previous
//
#include <hip/hip_runtime.h>
#include <hip/hip_bf16.h>
#include <stdint.h>

typedef __attribute__((ext_vector_type(4))) float  floatx4;
typedef __attribute__((ext_vector_type(8))) short  short8;
typedef __attribute__((ext_vector_type(8))) unsigned short ushortx8;
typedef __attribute__((ext_vector_type(4))) unsigned short ushortx4;

#define B_  2
#define T_  2048
#define E_  1024
#define H_  16
#define D_  64
#define C_  128
#define NC_ 16
#define M_  4096   /* B*T */
#define EPS_ 1e-5f

__device__ __forceinline__ unsigned short f2b(float f) {
    union { float f; unsigned int u; } v; v.f = f;
    unsigned int r = v.u + 0x7fffu + ((v.u >> 16) & 1u);
    return (unsigned short)(r >> 16);
}
__device__ __forceinline__ float b2f(unsigned short b) {
    union { unsigned int u; float f; } v; v.u = ((unsigned int)b) << 16;
    return v.f;
}

// Swizzled fragment staging (R3/R4):
//   staging lane i fetches global (row = i>>2, kseg = (i&3) ^ ((i>>3)&3)) -> LDS slot i (16B).
//   4-lane clusters cover one contiguous 64B line (coalesced) AND fragment reads
//   slot sigma(l) = m*4 + (q ^ ((m>>1)&3)) hit all 8 bank-quads per 8 lanes (0 conflicts).
__device__ __forceinline__ int stage_seg(int i) { return (i & 3) ^ ((i >> 3) & 3); }
__device__ __forceinline__ int frag_slot(int lane) {
    int m = lane & 15, q = lane >> 4;
    return m * 4 + (q ^ ((m >> 1) & 3));
}

// ---------------- fp32 -> bf16 convert (x) ----------------
__global__ __launch_bounds__(256) void convert_kernel(const float* __restrict__ src,
                                                      unsigned short* __restrict__ dst, int n) {
    int i = (blockIdx.x * 256 + threadIdx.x) * 4;
    if (i < n) {
        float4 f = *(const float4*)(src + i);
        ushortx4 o;
        o[0] = f2b(f.x); o[1] = f2b(f.y); o[2] = f2b(f.z); o[3] = f2b(f.w);
        *(ushortx4*)(dst + i) = o;
    }
}

// ---------------- fused 4-weight convert: Wq|Wk|Wv|Wo -> one contiguous bf16 region ----------------
__global__ __launch_bounds__(256) void convert4_kernel(const float* __restrict__ s0,
                                                       const float* __restrict__ s1,
                                                       const float* __restrict__ s2,
                                                       const float* __restrict__ s3,
                                                       unsigned short* __restrict__ dst) {
    int i = (blockIdx.x * 256 + threadIdx.x) * 4;   // over 4 * 1M elements
    int which = i >> 20;
    const float* s = (which == 0) ? s0 : (which == 1) ? s1 : (which == 2) ? s2 : s3;
    int off = i & ((1 << 20) - 1);
    float4 f = *(const float4*)(s + off);
    ushortx4 o;
    o[0] = f2b(f.x); o[1] = f2b(f.y); o[2] = f2b(f.z); o[3] = f2b(f.w);
    *(ushortx4*)(dst + i) = o;
}

// ---------------- QKV projection GEMM: C[4096,3072] = X @ W^T, phi on q,k ----------------
// BK=64: 16 K-iterations, 2 barriers each (vs 32 at BK=32) -> half the barrier drains.
// LDS 2 x 16 KB. Tile t = kh*8 + rt: rows [rt*16, rt*16+16), k [k0+kh*32, +32).
__global__ __launch_bounds__(256) void gemm_qkv(const unsigned short* __restrict__ A,
                                                const unsigned short* __restrict__ Bm,
                                                unsigned short* __restrict__ Cb) {
    const int N = 3 * E_, K = E_;
    __shared__ __align__(16) unsigned short at[16 * 512];
    __shared__ __align__(16) unsigned short bt[16 * 512];
    int tid = threadIdx.x;
    int wave = tid >> 6, lane = tid & 63;
    int wr = wave >> 1, wc = wave & 1;
    int m = lane & 15, q = lane >> 4;
    int srow = lane >> 2, sseg = stage_seg(lane);
    int fs = frag_slot(lane);
    int row0 = blockIdx.y * 128, col0 = blockIdx.x * 128;
    floatx4 acc[4][4];
    for (int i = 0; i < 4; i++) for (int j = 0; j < 4; j++) acc[i][j] = floatx4{0.f, 0.f, 0.f, 0.f};

    for (int k0 = 0; k0 < K; k0 += 64) {
        __syncthreads();
        for (int p = 0; p < 4; p++) {
            int t = p * 4 + wave;           // t in 0..15
            int rt = t & 7, kh = t >> 3;
            const unsigned short* ga = A  + (size_t)(row0 + rt * 16 + srow) * K + k0 + kh * 32 + sseg * 8;
            const unsigned short* gb = Bm + (size_t)(col0 + rt * 16 + srow) * K + k0 + kh * 32 + sseg * 8;
            __builtin_amdgcn_global_load_lds((const __attribute__((address_space(1))) unsigned int*)ga,
                (__attribute__((address_space(3))) unsigned int*)(at + t * 512), 16, 0, 0);
            __builtin_amdgcn_global_load_lds((const __attribute__((address_space(1))) unsigned int*)gb,
                (__attribute__((address_space(3))) unsigned int*)(bt + t * 512), 16, 0, 0);
        }
        __syncthreads();
        for (int kh = 0; kh < 2; kh++) {
            short8 af[4], bfr[4];
            for (int mi = 0; mi < 4; mi++) af[mi]  = *(const short8*)(at + (kh * 8 + wr * 4 + mi) * 512 + fs * 8);
            for (int ni = 0; ni < 4; ni++) bfr[ni] = *(const short8*)(bt + (kh * 8 + wc * 4 + ni) * 512 + fs * 8);
            for (int mi = 0; mi < 4; mi++)
                for (int ni = 0; ni < 4; ni++)
                    acc[mi][ni] = __builtin_amdgcn_mfma_f32_16x16x32_bf16(af[mi], bfr[ni], acc[mi][ni], 0, 0, 0);
        }
    }
    int qrow = q * 4;
    for (int mi = 0; mi < 4; mi++) for (int ni = 0; ni < 4; ni++) {
        int col = col0 + wc * 64 + ni * 16 + m;
        bool isphi = (col < 2 * E_);
        for (int r2 = 0; r2 < 4; r2++) {
            int row = row0 + wr * 64 + mi * 16 + qrow + r2;
            float v = acc[mi][ni][r2];
            if (isphi) v = (v > 0.f) ? (v + 1.f) : __expf(v);
            Cb[(size_t)row * N + col] = f2b(v);
        }
    }
}

// ---------------- Output GEMM: out[4096,1024] = attn @ Wo^T + bo (fp32 out) ----------------
// 64x128 block tile (512 blocks = 2/CU), BK=64 (24 KB LDS).
__global__ __launch_bounds__(256) void gemm_out(const unsigned short* __restrict__ A,
                                                const unsigned short* __restrict__ Bm,
                                                const float* __restrict__ bias,
                                                float* __restrict__ Cf) {
    const int N = E_, K = E_;
    __shared__ __align__(16) unsigned short at[8 * 512];    // 64 rows x 64 k
    __shared__ __align__(16) unsigned short bt[16 * 512];   // 128 rows x 64 k
    int tid = threadIdx.x;
    int wave = tid >> 6, lane = tid & 63;
    int m = lane & 15, q = lane >> 4;
    int srow = lane >> 2, sseg = stage_seg(lane);
    int fs = frag_slot(lane);
    int row0 = blockIdx.y * 64, col0 = blockIdx.x * 128;
    floatx4 acc[4][2];
    for (int i = 0; i < 4; i++) for (int j = 0; j < 2; j++) acc[i][j] = floatx4{0.f, 0.f, 0.f, 0.f};

    for (int k0 = 0; k0 < K; k0 += 64) {
        __syncthreads();
        for (int p = 0; p < 2; p++) {
            int ta = p * 4 + wave;          // 0..7 : rt = ta&3, kh = ta>>2
            int rta = ta & 3, kha = ta >> 2;
            const unsigned short* ga = A + (size_t)(row0 + rta * 16 + srow) * K + k0 + kha * 32 + sseg * 8;
            __builtin_amdgcn_global_load_lds((const __attribute__((address_space(1))) unsigned int*)ga,
                (__attribute__((address_space(3))) unsigned int*)(at + ta * 512), 16, 0, 0);
        }
        for (int p = 0; p < 4; p++) {
            int tb = p * 4 + wave;          // 0..15 : rt = tb&7, kh = tb>>3
            int rtb = tb & 7, khb = tb >> 3;
            const unsigned short* gb = Bm + (size_t)(col0 + rtb * 16 + srow) * K + k0 + khb * 32 + sseg * 8;
            __builtin_amdgcn_global_load_lds((const __attribute__((address_space(1))) unsigned int*)gb,
                (__attribute__((address_space(3))) unsigned int*)(bt + tb * 512), 16, 0, 0);
        }
        __syncthreads();
        for (int kh = 0; kh < 2; kh++) {
            short8 af[4], bfr[2];
            for (int mi = 0; mi < 4; mi++) af[mi]  = *(const short8*)(at + (kh * 4 + mi) * 512 + fs * 8);
            for (int ci = 0; ci < 2; ci++) bfr[ci] = *(const short8*)(bt + (kh * 8 + wave * 2 + ci) * 512 + fs * 8);
            for (int mi = 0; mi < 4; mi++)
                for (int ci = 0; ci < 2; ci++)
                    acc[mi][ci] = __builtin_amdgcn_mfma_f32_16x16x32_bf16(af[mi], bfr[ci], acc[mi][ci], 0, 0, 0);
        }
    }
    int qrow = q * 4;
    for (int ci = 0; ci < 2; ci++) {
        int col = col0 + wave * 32 + ci * 16 + m;
        float bv = bias[col];
        for (int mi = 0; mi < 4; mi++)
            for (int r2 = 0; r2 < 4; r2++) {
                int row = row0 + mi * 16 + qrow + r2;
                Cf[(size_t)row * N + col] = acc[mi][ci][r2] + bv;
            }
    }
}

// ---------------- per-chunk S_c = k_c^T v_c (64x64) and z_c (MFMA) ----------------
// A = K^T (m=d, k=t), B = V (k=t, n=e); extra n-col 64 = ones -> z_c.
__global__ __launch_bounds__(256) void chunk_sums(const unsigned short* __restrict__ qkv,
                                                  float* __restrict__ Sc, float* __restrict__ zc) {
    int c = blockIdx.x, h = blockIdx.y, bb = blockIdx.z;
    __shared__ __align__(16) unsigned short Kt[64 * 132];   // K^T: [d][t], stride 132 (conflict-free)
    __shared__ __align__(16) unsigned short Vt[80 * 132];   // V^T rows 0..63; row 64 = ones
    int tid = threadIdx.x;
    int lane = tid & 63, w = tid >> 6;
    size_t rowb = (size_t)bb * T_ + (size_t)c * C_;
    int kcol = E_ + h * D_, vcol = 2 * E_ + h * D_;

    for (int s = 0; s < 4; s++) {
        int off = s * 256 + tid;
        int r = off >> 3, seg = (off & 7) * 8;
        size_t g = (rowb + r) * 3072;
        ushortx8 k8 = *(const ushortx8*)(qkv + g + kcol + seg);
        ushortx8 v8 = *(const ushortx8*)(qkv + g + vcol + seg);
        for (int e = 0; e < 8; e++) {
            Kt[(seg + e) * 132 + r] = k8[e];
            Vt[(seg + e) * 132 + r] = v8[e];
        }
    }
    if (tid < 128) Vt[64 * 132 + tid] = 0x3f80;  // ones row (bf16 1.0)
    __syncthreads();

    floatx4 acc[5];
    for (int ni = 0; ni < 5; ni++) acc[ni] = floatx4{0.f, 0.f, 0.f, 0.f};
    int lm = lane & 15, lk = (lane >> 4) * 8;
    for (int k0 = 0; k0 < 128; k0 += 32) {
        short8 af = *(const short8*)(Kt + (w * 16 + lm) * 132 + k0 + lk);
        for (int ni = 0; ni < 5; ni++) {
            short8 bf = *(const short8*)(Vt + (ni * 16 + lm) * 132 + k0 + lk);
            acc[ni] = __builtin_amdgcn_mfma_f32_16x16x32_bf16(af, bf, acc[ni], 0, 0, 0);
        }
    }
    size_t base = ((size_t)(bb * H_ + h) * NC_ + c) * (size_t)(D_ * D_);
    int r0 = w * 16 + (lane >> 4) * 4;
    for (int ni = 0; ni < 4; ni++)
        for (int reg = 0; reg < 4; reg++)
            Sc[base + (size_t)(r0 + reg) * D_ + ni * 16 + lm] = acc[ni][reg];
    if (lm == 0) {
        size_t zb = ((size_t)(bb * H_ + h) * NC_ + c) * D_;
        for (int reg = 0; reg < 4; reg++) zc[zb + r0 + reg] = acc[4][reg];
    }
}

// ---------------- per-chunk attention (MFMA) ----------------
__global__ __launch_bounds__(256) void attn_kernel(const unsigned short* __restrict__ qkv,
                                                   const float* __restrict__ Sc,
                                                   const float* __restrict__ zc,
                                                   unsigned short* __restrict__ attn) {
    int c = blockIdx.x, h = blockIdx.y, bb = blockIdx.z;
    __shared__ __align__(16) unsigned short qs[128 * 68];   // Q row-major, stride 68
    __shared__ __align__(16) unsigned short ks[128 * 68];   // K row-major
    __shared__ __align__(16) unsigned short vt[64 * 132];   // V^T
    __shared__ __align__(16) unsigned short ovl[128 * 36];  // phase A: S_prev^T (stride 68); j-loop: P panel (stride 36)
    __shared__ float zsh[64];
    int tid = threadIdx.x;
    int lane = tid & 63, w = tid >> 6;
    int lm = lane & 15, lq = lane >> 4;
    size_t rowb = (size_t)bb * T_ + (size_t)c * C_;
    int qcol = h * D_, kcol = E_ + h * D_, vcol = 2 * E_ + h * D_;

    // ---- stage q, k (row-major) and v (transposed) ----
    for (int s = 0; s < 4; s++) {
        int off = s * 256 + tid;
        int r = off >> 3, seg = (off & 7) * 8;
        size_t g = (rowb + r) * 3072;
        ushortx8 q8 = *(const ushortx8*)(qkv + g + qcol + seg);
        ushortx8 k8 = *(const ushortx8*)(qkv + g + kcol + seg);
        ushortx8 v8 = *(const ushortx8*)(qkv + g + vcol + seg);
        *(ushortx8*)(qs + r * 68 + seg) = q8;
        *(ushortx8*)(ks + r * 68 + seg) = k8;
        for (int e = 0; e < 8; e++) vt[(seg + e) * 132 + r] = v8[e];
    }
    // ---- S_prev = sum_{j<c} Sc[j]  (store transposed bf16 into ovl, stride 68) ----
    {
        size_t scb = ((size_t)(bb * H_ + h) * NC_) * (size_t)(D_ * D_);
        int p = tid * 16;
        float a[16];
        for (int i = 0; i < 16; i++) a[i] = 0.f;
        for (int j = 0; j < c; j++) {
            const float* Sj = Sc + scb + (size_t)j * (D_ * D_) + p;
            for (int q = 0; q < 16; q += 4) {
                float4 f = *(const float4*)(Sj + q);
                a[q] += f.x; a[q + 1] += f.y; a[q + 2] += f.z; a[q + 3] += f.w;
            }
        }
        for (int i = 0; i < 16; i++) {
            int d = (p + i) >> 6, e = (p + i) & 63;
            ovl[e * 68 + d] = f2b(a[i]);
        }
    }
    // ---- z_prev (fp32) ----
    if (tid < 64) {
        size_t zb = ((size_t)(bb * H_ + h) * NC_) * D_;
        float zr = 0.f;
        for (int j = 0; j < c; j++) zr += zc[zb + (size_t)j * D_ + tid];
        zsh[tid] = zr;
    }
    __syncthreads();

    // ---- phase A: acc = Q @ S_prev  (wave w -> rows [w*32, w*32+32)) ----
    floatx4 acc[2][4];
    for (int mi = 0; mi < 2; mi++) for (int ni = 0; ni < 4; ni++) acc[mi][ni] = floatx4{0.f, 0.f, 0.f, 0.f};
    for (int k0 = 0; k0 < 64; k0 += 32) {
        short8 aq[2];
        for (int mi = 0; mi < 2; mi++)
            aq[mi] = *(const short8*)(qs + (w * 32 + mi * 16 + lm) * 68 + k0 + lq * 8);
        for (int ni = 0; ni < 4; ni++) {
            short8 bs = *(const short8*)(ovl + (ni * 16 + lm) * 68 + k0 + lq * 8);
            for (int mi = 0; mi < 2; mi++)
                acc[mi][ni] = __builtin_amdgcn_mfma_f32_16x16x32_bf16(aq[mi], bs, acc[mi][ni], 0, 0, 0);
        }
    }
    // ---- dsum init: q . z_prev per output row (C-layout rows), fp32 ----
    float dsum[2][4];
    {
        int d0 = lm * 4;
        float4 z4 = *(const float4*)(zsh + d0);
        for (int mi = 0; mi < 2; mi++)
            for (int reg = 0; reg < 4; reg++) {
                int row = w * 32 + mi * 16 + lq * 4 + reg;
                ushortx4 q4 = *(const ushortx4*)(qs + row * 68 + d0);
                dsum[mi][reg] = b2f(q4[0]) * z4.x + b2f(q4[1]) * z4.y + b2f(q4[2]) * z4.z + b2f(q4[3]) * z4.w;
            }
    }
    __syncthreads();  // all waves done reading S_prev^T from ovl before P writes

    // ---- intra-chunk j-loop: wave w only needs j-tiles jt <= w (causality) ----
    for (int jt = 0; jt <= w; jt++) {
        floatx4 pa[2][2];
        for (int mi = 0; mi < 2; mi++) for (int ct = 0; ct < 2; ct++) pa[mi][ct] = floatx4{0.f, 0.f, 0.f, 0.f};
        for (int k0 = 0; k0 < 64; k0 += 32) {
            short8 aq[2];
            for (int mi = 0; mi < 2; mi++)
                aq[mi] = *(const short8*)(qs + (w * 32 + mi * 16 + lm) * 68 + k0 + lq * 8);
            for (int ct = 0; ct < 2; ct++) {
                short8 bk = *(const short8*)(ks + (jt * 32 + ct * 16 + lm) * 68 + k0 + lq * 8);
                for (int mi = 0; mi < 2; mi++)
                    pa[mi][ct] = __builtin_amdgcn_mfma_f32_16x16x32_bf16(aq[mi], bk, pa[mi][ct], 0, 0, 0);
            }
        }
        bool diag = (jt == w);
        for (int mi = 0; mi < 2; mi++)
            for (int ct = 0; ct < 2; ct++)
                for (int reg = 0; reg < 4; reg++) {
                    int il = mi * 16 + lq * 4 + reg;   // row within wave's 32
                    int jl = ct * 16 + lm;             // col within j-tile's 32
                    float v = pa[mi][ct][reg];
                    if (diag && jl > il) v = 0.f;
                    dsum[mi][reg] += v;
                    ovl[(w * 32 + il) * 36 + jl] = f2b(v);
                }
        // PV: P (A-layout from own rows of ovl) x V^T slice, K=32
        short8 ap[2];
        for (int mi = 0; mi < 2; mi++)
            ap[mi] = *(const short8*)(ovl + (w * 32 + mi * 16 + lm) * 36 + lq * 8);
        for (int ni = 0; ni < 4; ni++) {
            short8 bv = *(const short8*)(vt + (ni * 16 + lm) * 132 + jt * 32 + lq * 8);
            for (int mi = 0; mi < 2; mi++)
                acc[mi][ni] = __builtin_amdgcn_mfma_f32_16x16x32_bf16(ap[mi], bv, acc[mi][ni], 0, 0, 0);
        }
    }

    // ---- reduce dsum across the 16-lane col group ----
    for (int off = 1; off < 16; off <<= 1)
        for (int mi = 0; mi < 2; mi++)
            for (int reg = 0; reg < 4; reg++)
                dsum[mi][reg] += __shfl_xor(dsum[mi][reg], off);

    // ---- epilogue: out = num / den ----
    for (int mi = 0; mi < 2; mi++)
        for (int reg = 0; reg < 4; reg++) {
            float inv = 1.f / (dsum[mi][reg] + EPS_);
            int row = w * 32 + mi * 16 + lq * 4 + reg;
            for (int ni = 0; ni < 4; ni++)
                attn[(rowb + row) * E_ + h * D_ + ni * 16 + lm] = f2b(acc[mi][ni][reg] * inv);
        }
}

extern "C" void kernel_launch(void* const* d_in, const int* in_sizes, int n_in,
                              void* d_out, int out_size, void* d_ws, size_t ws_size,
                              hipStream_t stream) {
    const float* x  = (const float*)d_in[0];
    const float* Wq = (const float*)d_in[1];
    const float* Wk = (const float*)d_in[2];
    const float* Wv = (const float*)d_in[3];
    const float* Wo = (const float*)d_in[4];
    const float* bo = (const float*)d_in[5];
    float* out = (float*)d_out;

    const size_t MB = 1024 * 1024;
    uint8_t* ws = (uint8_t*)d_ws;
    unsigned short* xb    = (unsigned short*)(ws + 0);        // 8 MB, reused as attn buffer
    unsigned short* wb    = (unsigned short*)(ws + 8 * MB);   // 8 MB (Wq|Wk|Wv|Wo bf16, contiguous)
    unsigned short* wob   = wb + 3 * E_ * E_;
    unsigned short* qkvb  = (unsigned short*)(ws + 16 * MB);  // 24 MB
    float* Sc = (float*)(ws + 40 * MB);                       // 8 MB
    float* zc = (float*)(ws + 48 * MB);                       // 128 KB
    unsigned short* attnb = xb;

    convert_kernel<<<(M_ * E_) / 1024, 256, 0, stream>>>(x, xb, M_ * E_);
    convert4_kernel<<<(4 * E_ * E_) / 1024, 256, 0, stream>>>(Wq, Wk, Wv, Wo, wb);

    gemm_qkv<<<dim3(24, 32), 256, 0, stream>>>(xb, wb, qkvb);
    chunk_sums<<<dim3(NC_, H_, B_), 256, 0, stream>>>(qkvb, Sc, zc);
    attn_kernel<<<dim3(NC_, H_, B_), 256, 0, stream>>>(qkvb, Sc, zc, attnb);
    gemm_out<<<dim3(8, 64), 256, 0, stream>>>(attnb, wob, bo, out);
}

// Round 6
// 166.201 us; speedup vs baseline: 1.2859x; 1.0526x over previous
//
#include <hip/hip_runtime.h>
#include <hip/hip_bf16.h>
#include <stdint.h>

typedef __attribute__((ext_vector_type(4))) float  floatx4;
typedef __attribute__((ext_vector_type(8))) short  short8;
typedef __attribute__((ext_vector_type(8))) unsigned short ushortx8;
typedef __attribute__((ext_vector_type(4))) unsigned short ushortx4;

#define B_  2
#define T_  2048
#define E_  1024
#define H_  16
#define D_  64
#define C_  128
#define NC_ 16
#define M_  4096   /* B*T */
#define EPS_ 1e-5f

__device__ __forceinline__ unsigned short f2b(float f) {
    union { float f; unsigned int u; } v; v.f = f;
    unsigned int r = v.u + 0x7fffu + ((v.u >> 16) & 1u);
    return (unsigned short)(r >> 16);
}
__device__ __forceinline__ float b2f(unsigned short b) {
    union { unsigned int u; float f; } v; v.u = ((unsigned int)b) << 16;
    return v.f;
}

// Swizzled fragment staging (R3/R4):
//   staging lane i fetches global (row = i>>2, kseg = (i&3) ^ ((i>>3)&3)) -> LDS slot i (16B).
//   4-lane clusters cover one contiguous 64B line (coalesced) AND fragment reads
//   slot sigma(l) = m*4 + (q ^ ((m>>1)&3)) hit all 8 bank-quads per 8 lanes (0 conflicts).
__device__ __forceinline__ int stage_seg(int i) { return (i & 3) ^ ((i >> 3) & 3); }
__device__ __forceinline__ int frag_slot(int lane) {
    int m = lane & 15, q = lane >> 4;
    return m * 4 + (q ^ ((m >> 1) & 3));
}

// ---------------- fused fp32 -> bf16 convert: x | Wq | Wk | Wv | Wo ----------------
// dst is one contiguous region (xb at ws+0, wb at ws+8MB): first 4M elems = x, then 4 x 1M weights.
__global__ __launch_bounds__(256) void convert_all(const float* __restrict__ x,
                                                   const float* __restrict__ Wq,
                                                   const float* __restrict__ Wk,
                                                   const float* __restrict__ Wv,
                                                   const float* __restrict__ Wo,
                                                   unsigned short* __restrict__ dst) {
    int i = (blockIdx.x * 256 + threadIdx.x) * 4;
    const float* s; int off;
    if (i < M_ * E_) { s = x; off = i; }
    else {
        int j = i - M_ * E_;
        int which = j >> 20;
        s = (which == 0) ? Wq : (which == 1) ? Wk : (which == 2) ? Wv : Wo;
        off = j & ((1 << 20) - 1);
    }
    float4 f = *(const float4*)(s + off);
    ushortx4 o;
    o[0] = f2b(f.x); o[1] = f2b(f.y); o[2] = f2b(f.z); o[3] = f2b(f.w);
    *(ushortx4*)(dst + i) = o;
}

// ---------------- QKV projection GEMM: C[4096,3072] = X @ W^T, phi on q,k ----------------
// 64x128 tile, BK=64 -> grid 24x64 = 1536 blocks = 6/CU (R5 was 3/CU and barrier-drain
// bound with all pipes <50%; more co-resident blocks hide the vmcnt(0) drain).
// LDS 24 KB: at 8 tiles (64r x 64k), bt 16 tiles (128c x 64k). Tile t: rows 16, k 32.
__global__ __launch_bounds__(256) void gemm_qkv(const unsigned short* __restrict__ A,
                                                const unsigned short* __restrict__ Bm,
                                                unsigned short* __restrict__ Cb) {
    const int N = 3 * E_, K = E_;
    __shared__ __align__(16) unsigned short at[8 * 512];
    __shared__ __align__(16) unsigned short bt[16 * 512];
    int tid = threadIdx.x;
    int wave = tid >> 6, lane = tid & 63;
    int wr = wave >> 1, wc = wave & 1;
    int m = lane & 15, q = lane >> 4;
    int srow = lane >> 2, sseg = stage_seg(lane);
    int fs = frag_slot(lane);
    int row0 = blockIdx.y * 64, col0 = blockIdx.x * 128;
    floatx4 acc[2][4];
    for (int i = 0; i < 2; i++) for (int j = 0; j < 4; j++) acc[i][j] = floatx4{0.f, 0.f, 0.f, 0.f};

    for (int k0 = 0; k0 < K; k0 += 64) {
        __syncthreads();
        for (int p = 0; p < 2; p++) {               // A: 8 tiles, 2 per wave
            int t = p * 4 + wave;
            int rt = t & 3, kh = t >> 2;
            const unsigned short* ga = A + (size_t)(row0 + rt * 16 + srow) * K + k0 + kh * 32 + sseg * 8;
            __builtin_amdgcn_global_load_lds((const __attribute__((address_space(1))) unsigned int*)ga,
                (__attribute__((address_space(3))) unsigned int*)(at + t * 512), 16, 0, 0);
        }
        for (int p = 0; p < 4; p++) {               // B: 16 tiles, 4 per wave
            int t = p * 4 + wave;
            int rt = t & 7, kh = t >> 3;
            const unsigned short* gb = Bm + (size_t)(col0 + rt * 16 + srow) * K + k0 + kh * 32 + sseg * 8;
            __builtin_amdgcn_global_load_lds((const __attribute__((address_space(1))) unsigned int*)gb,
                (__attribute__((address_space(3))) unsigned int*)(bt + t * 512), 16, 0, 0);
        }
        __syncthreads();
        for (int kh = 0; kh < 2; kh++) {
            short8 af[2], bfr[4];
            for (int mi = 0; mi < 2; mi++) af[mi]  = *(const short8*)(at + (kh * 4 + wr * 2 + mi) * 512 + fs * 8);
            for (int ni = 0; ni < 4; ni++) bfr[ni] = *(const short8*)(bt + (kh * 8 + wc * 4 + ni) * 512 + fs * 8);
            for (int mi = 0; mi < 2; mi++)
                for (int ni = 0; ni < 4; ni++)
                    acc[mi][ni] = __builtin_amdgcn_mfma_f32_16x16x32_bf16(af[mi], bfr[ni], acc[mi][ni], 0, 0, 0);
        }
    }
    int qrow = q * 4;
    for (int mi = 0; mi < 2; mi++) for (int ni = 0; ni < 4; ni++) {
        int col = col0 + wc * 64 + ni * 16 + m;
        bool isphi = (col < 2 * E_);
        for (int r2 = 0; r2 < 4; r2++) {
            int row = row0 + wr * 32 + mi * 16 + qrow + r2;
            float v = acc[mi][ni][r2];
            if (isphi) v = (v > 0.f) ? (v + 1.f) : __expf(v);
            Cb[(size_t)row * N + col] = f2b(v);
        }
    }
}

// ---------------- Output GEMM: out[4096,1024] = attn @ Wo^T + bo (fp32 out) ----------------
// 64x64 tile, BK=64 -> grid 16x64 = 1024 blocks = 4/CU, LDS 16 KB.
__global__ __launch_bounds__(256) void gemm_out(const unsigned short* __restrict__ A,
                                                const unsigned short* __restrict__ Bm,
                                                const float* __restrict__ bias,
                                                float* __restrict__ Cf) {
    const int N = E_, K = E_;
    __shared__ __align__(16) unsigned short at[8 * 512];
    __shared__ __align__(16) unsigned short bt[8 * 512];
    int tid = threadIdx.x;
    int wave = tid >> 6, lane = tid & 63;
    int wr = wave >> 1, wc = wave & 1;
    int m = lane & 15, q = lane >> 4;
    int srow = lane >> 2, sseg = stage_seg(lane);
    int fs = frag_slot(lane);
    int row0 = blockIdx.y * 64, col0 = blockIdx.x * 64;
    floatx4 acc[2][2];
    for (int i = 0; i < 2; i++) for (int j = 0; j < 2; j++) acc[i][j] = floatx4{0.f, 0.f, 0.f, 0.f};

    for (int k0 = 0; k0 < K; k0 += 64) {
        __syncthreads();
        for (int p = 0; p < 2; p++) {
            int t = p * 4 + wave;
            int rt = t & 3, kh = t >> 2;
            const unsigned short* ga = A  + (size_t)(row0 + rt * 16 + srow) * K + k0 + kh * 32 + sseg * 8;
            const unsigned short* gb = Bm + (size_t)(col0 + rt * 16 + srow) * K + k0 + kh * 32 + sseg * 8;
            __builtin_amdgcn_global_load_lds((const __attribute__((address_space(1))) unsigned int*)ga,
                (__attribute__((address_space(3))) unsigned int*)(at + t * 512), 16, 0, 0);
            __builtin_amdgcn_global_load_lds((const __attribute__((address_space(1))) unsigned int*)gb,
                (__attribute__((address_space(3))) unsigned int*)(bt + t * 512), 16, 0, 0);
        }
        __syncthreads();
        for (int kh = 0; kh < 2; kh++) {
            short8 af[2], bfr[2];
            for (int mi = 0; mi < 2; mi++) af[mi]  = *(const short8*)(at + (kh * 4 + wr * 2 + mi) * 512 + fs * 8);
            for (int ci = 0; ci < 2; ci++) bfr[ci] = *(const short8*)(bt + (kh * 4 + wc * 2 + ci) * 512 + fs * 8);
            for (int mi = 0; mi < 2; mi++)
                for (int ci = 0; ci < 2; ci++)
                    acc[mi][ci] = __builtin_amdgcn_mfma_f32_16x16x32_bf16(af[mi], bfr[ci], acc[mi][ci], 0, 0, 0);
        }
    }
    int qrow = q * 4;
    for (int ci = 0; ci < 2; ci++) {
        int col = col0 + wc * 32 + ci * 16 + m;
        float bv = bias[col];
        for (int mi = 0; mi < 2; mi++)
            for (int r2 = 0; r2 < 4; r2++) {
                int row = row0 + wr * 32 + mi * 16 + qrow + r2;
                Cf[(size_t)row * N + col] = acc[mi][ci][r2] + bv;
            }
    }
}

// ---------------- per-chunk S_c = k_c^T v_c (64x64) and z_c (MFMA) ----------------
// A = K^T (m=d, k=t), B = V (k=t, n=e); extra n-col 64 = ones -> z_c.
__global__ __launch_bounds__(256) void chunk_sums(const unsigned short* __restrict__ qkv,
                                                  float* __restrict__ Sc, float* __restrict__ zc) {
    int c = blockIdx.x, h = blockIdx.y, bb = blockIdx.z;
    __shared__ __align__(16) unsigned short Kt[64 * 132];   // K^T: [d][t], stride 132 (conflict-free)
    __shared__ __align__(16) unsigned short Vt[80 * 132];   // V^T rows 0..63; row 64 = ones
    int tid = threadIdx.x;
    int lane = tid & 63, w = tid >> 6;
    size_t rowb = (size_t)bb * T_ + (size_t)c * C_;
    int kcol = E_ + h * D_, vcol = 2 * E_ + h * D_;

    for (int s = 0; s < 4; s++) {
        int off = s * 256 + tid;
        int r = off >> 3, seg = (off & 7) * 8;
        size_t g = (rowb + r) * 3072;
        ushortx8 k8 = *(const ushortx8*)(qkv + g + kcol + seg);
        ushortx8 v8 = *(const ushortx8*)(qkv + g + vcol + seg);
        for (int e = 0; e < 8; e++) {
            Kt[(seg + e) * 132 + r] = k8[e];
            Vt[(seg + e) * 132 + r] = v8[e];
        }
    }
    if (tid < 128) Vt[64 * 132 + tid] = 0x3f80;  // ones row (bf16 1.0)
    __syncthreads();

    floatx4 acc[5];
    for (int ni = 0; ni < 5; ni++) acc[ni] = floatx4{0.f, 0.f, 0.f, 0.f};
    int lm = lane & 15, lk = (lane >> 4) * 8;
    for (int k0 = 0; k0 < 128; k0 += 32) {
        short8 af = *(const short8*)(Kt + (w * 16 + lm) * 132 + k0 + lk);
        for (int ni = 0; ni < 5; ni++) {
            short8 bf = *(const short8*)(Vt + (ni * 16 + lm) * 132 + k0 + lk);
            acc[ni] = __builtin_amdgcn_mfma_f32_16x16x32_bf16(af, bf, acc[ni], 0, 0, 0);
        }
    }
    size_t base = ((size_t)(bb * H_ + h) * NC_ + c) * (size_t)(D_ * D_);
    int r0 = w * 16 + (lane >> 4) * 4;
    for (int ni = 0; ni < 4; ni++)
        for (int reg = 0; reg < 4; reg++)
            Sc[base + (size_t)(r0 + reg) * D_ + ni * 16 + lm] = acc[ni][reg];
    if (lm == 0) {
        size_t zb = ((size_t)(bb * H_ + h) * NC_ + c) * D_;
        for (int reg = 0; reg < 4; reg++) zc[zb + r0 + reg] = acc[4][reg];
    }
}

// ---------------- per-chunk attention (MFMA) ----------------
__global__ __launch_bounds__(256) void attn_kernel(const unsigned short* __restrict__ qkv,
                                                   const float* __restrict__ Sc,
                                                   const float* __restrict__ zc,
                                                   unsigned short* __restrict__ attn) {
    int c = blockIdx.x, h = blockIdx.y, bb = blockIdx.z;
    __shared__ __align__(16) unsigned short qs[128 * 68];   // Q row-major, stride 68
    __shared__ __align__(16) unsigned short ks[128 * 68];   // K row-major
    __shared__ __align__(16) unsigned short vt[64 * 132];   // V^T
    __shared__ __align__(16) unsigned short ovl[128 * 36];  // phase A: S_prev^T (stride 68); j-loop: P panel (stride 36)
    __shared__ float zsh[64];
    int tid = threadIdx.x;
    int lane = tid & 63, w = tid >> 6;
    int lm = lane & 15, lq = lane >> 4;
    size_t rowb = (size_t)bb * T_ + (size_t)c * C_;
    int qcol = h * D_, kcol = E_ + h * D_, vcol = 2 * E_ + h * D_;

    // ---- stage q, k (row-major) and v (transposed) ----
    for (int s = 0; s < 4; s++) {
        int off = s * 256 + tid;
        int r = off >> 3, seg = (off & 7) * 8;
        size_t g = (rowb + r) * 3072;
        ushortx8 q8 = *(const ushortx8*)(qkv + g + qcol + seg);
        ushortx8 k8 = *(const ushortx8*)(qkv + g + kcol + seg);
        ushortx8 v8 = *(const ushortx8*)(qkv + g + vcol + seg);
        *(ushortx8*)(qs + r * 68 + seg) = q8;
        *(ushortx8*)(ks + r * 68 + seg) = k8;
        for (int e = 0; e < 8; e++) vt[(seg + e) * 132 + r] = v8[e];
    }
    // ---- S_prev = sum_{j<c} Sc[j]  (store transposed bf16 into ovl, stride 68) ----
    {
        size_t scb = ((size_t)(bb * H_ + h) * NC_) * (size_t)(D_ * D_);
        int p = tid * 16;
        float a[16];
        for (int i = 0; i < 16; i++) a[i] = 0.f;
        for (int j = 0; j < c; j++) {
            const float* Sj = Sc + scb + (size_t)j * (D_ * D_) + p;
            for (int q = 0; q < 16; q += 4) {
                float4 f = *(const float4*)(Sj + q);
                a[q] += f.x; a[q + 1] += f.y; a[q + 2] += f.z; a[q + 3] += f.w;
            }
        }
        for (int i = 0; i < 16; i++) {
            int d = (p + i) >> 6, e = (p + i) & 63;
            ovl[e * 68 + d] = f2b(a[i]);
        }
    }
    // ---- z_prev (fp32) ----
    if (tid < 64) {
        size_t zb = ((size_t)(bb * H_ + h) * NC_) * D_;
        float zr = 0.f;
        for (int j = 0; j < c; j++) zr += zc[zb + (size_t)j * D_ + tid];
        zsh[tid] = zr;
    }
    __syncthreads();

    // ---- phase A: acc = Q @ S_prev  (wave w -> rows [w*32, w*32+32)) ----
    floatx4 acc[2][4];
    for (int mi = 0; mi < 2; mi++) for (int ni = 0; ni < 4; ni++) acc[mi][ni] = floatx4{0.f, 0.f, 0.f, 0.f};
    for (int k0 = 0; k0 < 64; k0 += 32) {
        short8 aq[2];
        for (int mi = 0; mi < 2; mi++)
            aq[mi] = *(const short8*)(qs + (w * 32 + mi * 16 + lm) * 68 + k0 + lq * 8);
        for (int ni = 0; ni < 4; ni++) {
            short8 bs = *(const short8*)(ovl + (ni * 16 + lm) * 68 + k0 + lq * 8);
            for (int mi = 0; mi < 2; mi++)
                acc[mi][ni] = __builtin_amdgcn_mfma_f32_16x16x32_bf16(aq[mi], bs, acc[mi][ni], 0, 0, 0);
        }
    }
    // ---- dsum init: q . z_prev per output row (C-layout rows), fp32 ----
    float dsum[2][4];
    {
        int d0 = lm * 4;
        float4 z4 = *(const float4*)(zsh + d0);
        for (int mi = 0; mi < 2; mi++)
            for (int reg = 0; reg < 4; reg++) {
                int row = w * 32 + mi * 16 + lq * 4 + reg;
                ushortx4 q4 = *(const ushortx4*)(qs + row * 68 + d0);
                dsum[mi][reg] = b2f(q4[0]) * z4.x + b2f(q4[1]) * z4.y + b2f(q4[2]) * z4.z + b2f(q4[3]) * z4.w;
            }
    }
    __syncthreads();  // all waves done reading S_prev^T from ovl before P writes

    // ---- intra-chunk j-loop: wave w only needs j-tiles jt <= w (causality) ----
    for (int jt = 0; jt <= w; jt++) {
        floatx4 pa[2][2];
        for (int mi = 0; mi < 2; mi++) for (int ct = 0; ct < 2; ct++) pa[mi][ct] = floatx4{0.f, 0.f, 0.f, 0.f};
        for (int k0 = 0; k0 < 64; k0 += 32) {
            short8 aq[2];
            for (int mi = 0; mi < 2; mi++)
                aq[mi] = *(const short8*)(qs + (w * 32 + mi * 16 + lm) * 68 + k0 + lq * 8);
            for (int ct = 0; ct < 2; ct++) {
                short8 bk = *(const short8*)(ks + (jt * 32 + ct * 16 + lm) * 68 + k0 + lq * 8);
                for (int mi = 0; mi < 2; mi++)
                    pa[mi][ct] = __builtin_amdgcn_mfma_f32_16x16x32_bf16(aq[mi], bk, pa[mi][ct], 0, 0, 0);
            }
        }
        bool diag = (jt == w);
        for (int mi = 0; mi < 2; mi++)
            for (int ct = 0; ct < 2; ct++)
                for (int reg = 0; reg < 4; reg++) {
                    int il = mi * 16 + lq * 4 + reg;   // row within wave's 32
                    int jl = ct * 16 + lm;             // col within j-tile's 32
                    float v = pa[mi][ct][reg];
                    if (diag && jl > il) v = 0.f;
                    dsum[mi][reg] += v;
                    ovl[(w * 32 + il) * 36 + jl] = f2b(v);
                }
        // PV: P (A-layout from own rows of ovl) x V^T slice, K=32
        short8 ap[2];
        for (int mi = 0; mi < 2; mi++)
            ap[mi] = *(const short8*)(ovl + (w * 32 + mi * 16 + lm) * 36 + lq * 8);
        for (int ni = 0; ni < 4; ni++) {
            short8 bv = *(const short8*)(vt + (ni * 16 + lm) * 132 + jt * 32 + lq * 8);
            for (int mi = 0; mi < 2; mi++)
                acc[mi][ni] = __builtin_amdgcn_mfma_f32_16x16x32_bf16(ap[mi], bv, acc[mi][ni], 0, 0, 0);
        }
    }

    // ---- reduce dsum across the 16-lane col group ----
    for (int off = 1; off < 16; off <<= 1)
        for (int mi = 0; mi < 2; mi++)
            for (int reg = 0; reg < 4; reg++)
                dsum[mi][reg] += __shfl_xor(dsum[mi][reg], off);

    // ---- epilogue: out = num / den ----
    for (int mi = 0; mi < 2; mi++)
        for (int reg = 0; reg < 4; reg++) {
            float inv = 1.f / (dsum[mi][reg] + EPS_);
            int row = w * 32 + mi * 16 + lq * 4 + reg;
            for (int ni = 0; ni < 4; ni++)
                attn[(rowb + row) * E_ + h * D_ + ni * 16 + lm] = f2b(acc[mi][ni][reg] * inv);
        }
}

extern "C" void kernel_launch(void* const* d_in, const int* in_sizes, int n_in,
                              void* d_out, int out_size, void* d_ws, size_t ws_size,
                              hipStream_t stream) {
    const float* x  = (const float*)d_in[0];
    const float* Wq = (const float*)d_in[1];
    const float* Wk = (const float*)d_in[2];
    const float* Wv = (const float*)d_in[3];
    const float* Wo = (const float*)d_in[4];
    const float* bo = (const float*)d_in[5];
    float* out = (float*)d_out;

    const size_t MB = 1024 * 1024;
    uint8_t* ws = (uint8_t*)d_ws;
    unsigned short* xb    = (unsigned short*)(ws + 0);        // 8 MB, reused as attn buffer
    unsigned short* wb    = (unsigned short*)(ws + 8 * MB);   // 8 MB (Wq|Wk|Wv|Wo bf16, contiguous with xb)
    unsigned short* wob   = wb + 3 * E_ * E_;
    unsigned short* qkvb  = (unsigned short*)(ws + 16 * MB);  // 24 MB
    float* Sc = (float*)(ws + 40 * MB);                       // 8 MB
    float* zc = (float*)(ws + 48 * MB);                       // 128 KB
    unsigned short* attnb = xb;

    convert_all<<<(M_ * E_ + 4 * E_ * E_) / 1024, 256, 0, stream>>>(x, Wq, Wk, Wv, Wo, xb);

    gemm_qkv<<<dim3(24, 64), 256, 0, stream>>>(xb, wb, qkvb);
    chunk_sums<<<dim3(NC_, H_, B_), 256, 0, stream>>>(qkvb, Sc, zc);
    attn_kernel<<<dim3(NC_, H_, B_), 256, 0, stream>>>(qkvb, Sc, zc, attnb);
    gemm_out<<<dim3(16, 64), 256, 0, stream>>>(attnb, wob, bo, out);
}